// Round 9
// baseline (389.138 us; speedup 1.0000x reference)
//
#include <hip/hip_runtime.h>
#include <math.h>

#define NE 64
#define NTOK 16384
#define DD 4096
#define TOPK 2
#define BLOCK 512             // 8 waves = 8 K-slices (per-wave-private staging)
#define TOKPB 64
#define NKQ 8
#define KRANGE (DD / NKQ)     // 512 k per wave
#define KC 16                 // k per chunk
#define NCH (KRANGE / KC)     // 32 chunks
#define LGSTR 68              // logit plane row stride (dwords)
#define LGPL (64 * LGSTR)     // 4352 dwords per plane
#define SMEM_DW (NKQ * LGPL)  // 34816 dw = 139.3 KB; staging aliases [0,32768)

// Per-wave staging region (dwords): base = kq*4096
//   xbuf(b) = base + b*1024      : 64 tok rows x 16 k (row = local token)
//   wbuf(b) = base + 2048 + b*1024 : 64 expert rows x 16 k
// Swizzle: LDS slot j (16B quad) of row r holds global quad j ^ ((r>>1)&3).
// Read quad Q of row r -> slot Q ^ ((r>>1)&3); for rows s+8t this is
// Q ^ ((s>>1)&3) (t-independent) -> 8 distinct rows cover all 32 banks.

__device__ __forceinline__ void dma16(const float* g, float* l) {
  __builtin_amdgcn_global_load_lds(
      (const __attribute__((address_space(1))) void*)g,
      (__attribute__((address_space(3))) void*)l, 16, 0, 0);
}

__global__ __launch_bounds__(BLOCK) void router_kernel(
    const float* __restrict__ x, const float* __restrict__ gw,
    float* __restrict__ out, float* __restrict__ ws) {
  __shared__ __align__(16) float smem[SMEM_DW];

  const int tid = threadIdx.x;
  const int lane = tid & 63;
  const int kq = __builtin_amdgcn_readfirstlane(tid >> 6);  // K slice
  const int g = lane >> 3;  // expert sub-row: experts g + 8j, j=0..7
  const int s = lane & 7;   // token slot: tokens s + 8t, t=0..7
  const int tok0 = blockIdx.x * TOKPB;

  // ---- DMA source addressing (per-lane, source pre-swizzled; dest linear) --
  const int swz = (lane & 3) ^ ((lane >> 3) & 3);  // uniform for all 4 instrs
  const float* pgx =
      x + (size_t)(tok0 + (lane >> 2)) * DD + kq * KRANGE + swz * 4;
  const float* pgw = gw + (size_t)(lane >> 2) * DD + kq * KRANGE + swz * 4;

  // ---- LDS read bases (bytes); buf/t/j offsets are compile-time imms ----
  const char* smb = (const char*)smem;
  int bx[4], bw[4];
#pragma unroll
  for (int Q = 0; Q < 4; ++Q) {
    bx[Q] = kq * 16384 + s * 64 + ((Q ^ (s >> 1)) & 3) * 16;
    bw[Q] = kq * 16384 + 8192 + g * 64 + ((Q ^ (g >> 1)) & 3) * 16;
  }

  float acc[8][8];
#pragma unroll
  for (int t = 0; t < 8; ++t)
#pragma unroll
    for (int j = 0; j < 8; ++j) acc[t][j] = 0.f;

#define ISSUE(BUF)                                                          \
  do {                                                                      \
    _Pragma("unroll") for (int i = 0; i < 4; ++i)                           \
        dma16(pgx + (size_t)i * 16 * DD,                                    \
              &smem[kq * 4096 + (BUF)*1024 + i * 256]);                     \
    _Pragma("unroll") for (int i = 0; i < 4; ++i)                           \
        dma16(pgw + (size_t)i * 16 * DD,                                    \
              &smem[kq * 4096 + 2048 + (BUF)*1024 + i * 256]);              \
  } while (0)

#define QUADOP(BUF, Q)                                                      \
  do {                                                                      \
    float4 xv[8];                                                           \
    _Pragma("unroll") for (int t = 0; t < 8; ++t) xv[t] =                   \
        *(const float4*)(smb + bx[Q] + (BUF)*4096 + t * 512);               \
    _Pragma("unroll") for (int j = 0; j < 8; ++j) {                         \
      const float4 w =                                                      \
          *(const float4*)(smb + bw[Q] + (BUF)*4096 + j * 512);             \
      _Pragma("unroll") for (int t = 0; t < 8; ++t) {                       \
        acc[t][j] = fmaf(xv[t].x, w.x, acc[t][j]);                          \
        acc[t][j] = fmaf(xv[t].y, w.y, acc[t][j]);                          \
        acc[t][j] = fmaf(xv[t].z, w.z, acc[t][j]);                          \
        acc[t][j] = fmaf(xv[t].w, w.w, acc[t][j]);                          \
      }                                                                     \
    }                                                                       \
  } while (0)

#define CHUNKCOMP(BUF) \
  QUADOP(BUF, 0);      \
  QUADOP(BUF, 1);      \
  QUADOP(BUF, 2);      \
  QUADOP(BUF, 3)

  // prologue: chunk 0 -> buf 0
  ISSUE(0);
  pgx += KC;
  pgw += KC;

  // main loop: per-wave pipeline, NO barriers (staging is wave-private;
  // counted vmcnt keeps next-chunk DMA in flight under current compute).
#pragma unroll 1
  for (int cc = 0; cc < NCH; cc += 2) {
    {  // chunk cc (buf 0); cc+1 < NCH always (NCH even)
      ISSUE(1);
      pgx += KC;
      pgw += KC;
      asm volatile("s_waitcnt vmcnt(8)" ::: "memory");
      CHUNKCOMP(0);
    }
    {  // chunk cc+1 (buf 1)
      if (cc + 2 < NCH) {
        ISSUE(0);
        pgx += KC;
        pgw += KC;
        asm volatile("s_waitcnt vmcnt(8)" ::: "memory");
      } else {
        asm volatile("s_waitcnt vmcnt(0)" ::: "memory");
      }
      CHUNKCOMP(1);
    }
  }
#undef CHUNKCOMP
#undef QUADOP
#undef ISSUE

  __syncthreads();  // all compute done; staging dies, logit planes alias

  // partial logits: plane[kq][tok 64][LGSTR]; token s+8t, expert g+8j
  {
    float* pl = &smem[kq * LGPL];
#pragma unroll
    for (int t = 0; t < 8; ++t)
#pragma unroll
      for (int j = 0; j < 8; ++j)
        pl[(s + 8 * t) * LGSTR + g + 8 * j] = acc[t][j];
  }
  __syncthreads();

  // epilogue: wave kq -> tokens kq*8..+7; lane == expert
  float psum_local = 0.f, cnt_local = 0.f;
  float* out_v = out;                // (NTOK, 2) top-k vals
  float* out_i = out + NTOK * TOPK;  // (NTOK, 2) top-k idx as float
#pragma unroll 1
  for (int ii = 0; ii < 8; ++ii) {
    const int t = kq * 8 + ii;
    float v = 0.f;
#pragma unroll
    for (int p = 0; p < NKQ; ++p) v += smem[p * LGPL + t * LGSTR + lane];
    float m = v;
#pragma unroll
    for (int sh = 32; sh > 0; sh >>= 1) m = fmaxf(m, __shfl_xor(m, sh, 64));
    float ex = expf(v - m);
    float ssum = ex;
#pragma unroll
    for (int sh = 32; sh > 0; sh >>= 1) ssum += __shfl_xor(ssum, sh, 64);
    float p = ex / ssum;
    psum_local += p;

    float v1 = p; int i1 = lane;  // top-1, ties -> lowest index
#pragma unroll
    for (int sh = 32; sh > 0; sh >>= 1) {
      float ov = __shfl_xor(v1, sh, 64);
      int oi = __shfl_xor(i1, sh, 64);
      if (ov > v1 || (ov == v1 && oi < i1)) { v1 = ov; i1 = oi; }
    }
    float v2 = (lane == i1) ? -INFINITY : p; int i2 = lane;  // top-2
#pragma unroll
    for (int sh = 32; sh > 0; sh >>= 1) {
      float ov = __shfl_xor(v2, sh, 64);
      int oi = __shfl_xor(i2, sh, 64);
      if (ov > v2 || (ov == v2 && oi < i2)) { v2 = ov; i2 = oi; }
    }
    cnt_local += (lane == i1 ? 1.f : 0.f) + (lane == i2 ? 1.f : 0.f);
    if (lane == 0) {
      const int tg = tok0 + t;
      out_v[tg * 2 + 0] = v1;
      out_v[tg * 2 + 1] = v2;
      out_i[tg * 2 + 0] = (float)i1;
      out_i[tg * 2 + 1] = (float)i2;
    }
  }
  // loss partials: ws[0:64] = pick counts, ws[64:128] = prob sums
  atomicAdd(ws + lane, cnt_local);
  atomicAdd(ws + NE + lane, psum_local);
}

__global__ void loss_kernel(const float* __restrict__ ws,
                            float* __restrict__ out) {
  const int lane = threadIdx.x & 63;
  float f = ws[lane] * (1.f / (float)(NTOK * TOPK));
  float p = ws[NE + lane] * (1.f / (float)NTOK);
  float v = f * p;  // loss = E * mean_i(f_i p_i) = sum_i f_i p_i
#pragma unroll
  for (int sh = 32; sh > 0; sh >>= 1) v += __shfl_xor(v, sh, 64);
  if (lane == 0) out[NTOK * TOPK * 2] = v;
}

extern "C" void kernel_launch(void* const* d_in, const int* in_sizes, int n_in,
                              void* d_out, int out_size, void* d_ws,
                              size_t ws_size, hipStream_t stream) {
  const float* x = (const float*)d_in[0];
  const float* gw = (const float*)d_in[1];
  float* out = (float*)d_out;
  float* ws = (float*)d_ws;

  hipMemsetAsync(d_ws, 0, 2 * NE * sizeof(float), stream);
  router_kernel<<<NTOK / TOKPB, BLOCK, 0, stream>>>(x, gw, out, ws);
  loss_kernel<<<1, 64, 0, stream>>>(ws, out);
}

// Round 10
// 214.930 us; speedup vs baseline: 1.8105x; 1.8105x over previous
//
#include <hip/hip_runtime.h>
#include <math.h>

#define NE 64
#define NTOK 16384
#define DD 4096
#define TOPK 2
#define BLOCK 512             // 8 waves = 4 K-slices x 2 token-halves
#define TOKPB 64
#define KQN 4
#define KRANGE (DD / KQN)     // 1024 k per wave
#define KC 16                 // k per chunk
#define NCH (KRANGE / KC)     // 64 chunks
#define LGSTR 68              // logit plane row stride (dwords)
#define LGPL (64 * LGSTR)     // 4352 dwords per plane
#define SMEM_DW (KQN * LGPL)  // 17408 dw = 69.6 KB; x staging aliases [0,8192)

// Hybrid operand feed (escapes the LDS-pipe wall measured in R8/R9):
//   x -> LDS via global_load_lds DMA (no VGPR staging), T=4 rows/lane
//   w -> per-lane global float4 from L2 (~200cyc, each feeds 16 FMAs), E=8
// Per-wave x staging: 32 tok rows x 16 k x 2 bufs = 1024 dw (4KB), PRIVATE ->
// no barriers in main loop. Swizzle (R9-verified, 0 conflicts): LDS 16B slot
// j of row r holds global quad j ^ ((r>>1)&3); DMA dest linear, source
// pre-swizzled by (lane&3)^((lane>>3)&3).

__device__ __forceinline__ void dma16(const float* g, float* l) {
  __builtin_amdgcn_global_load_lds(
      (const __attribute__((address_space(1))) void*)g,
      (__attribute__((address_space(3))) void*)l, 16, 0, 0);
}

__global__ __launch_bounds__(BLOCK) void router_kernel(
    const float* __restrict__ x, const float* __restrict__ gw,
    float* __restrict__ out, float* __restrict__ ws) {
  __shared__ __align__(16) float smem[SMEM_DW];

  const int tid = threadIdx.x;
  const int lane = tid & 63;
  const int wid = __builtin_amdgcn_readfirstlane(tid >> 6);
  const int kq = wid >> 1;  // K slice (KRANGE cols)
  const int h = wid & 1;    // token half (32 tokens)
  const int g = lane >> 3;  // expert sub-row: experts g + 8j, j=0..7
  const int s = lane & 7;   // token slot: tokens h*32 + s + 8t, t=0..3
  const int tok0 = blockIdx.x * TOKPB;

  // ---- x DMA source (per-lane, pre-swizzled; LDS dest wave-uniform+linear) --
  const int swz = (lane & 3) ^ ((lane >> 3) & 3);
  const float* pgx = x + (size_t)(tok0 + h * 32 + (lane >> 2)) * DD +
                     kq * KRANGE + swz * 4;
  const int sb = wid * 1024;  // staging dword base; buf b at +b*512

  // ---- w global row pointer (per-lane expert row g; j adds 8 rows) ----
  const float* wrow = gw + (size_t)g * DD + kq * KRANGE;

  // ---- x LDS read byte bases per quad (conflict-free swizzle) ----
  const char* smb = (const char*)smem;
  int bxq[4];
#pragma unroll
  for (int Q = 0; Q < 4; ++Q)
    bxq[Q] = wid * 4096 + s * 64 + (((Q ^ (s >> 1)) & 3) << 4);

  float acc[4][8];
#pragma unroll
  for (int t = 0; t < 4; ++t)
#pragma unroll
    for (int j = 0; j < 8; ++j) acc[t][j] = 0.f;

#define ISSUE(B, C)                                                         \
  do {                                                                      \
    dma16(pgx + (size_t)(C) * KC, &smem[sb + (B) * 512]);                   \
    dma16(pgx + (size_t)16 * DD + (size_t)(C) * KC,                         \
          &smem[sb + (B) * 512 + 256]);                                     \
  } while (0)

#define QUADOP(B, Q, KO)                                                    \
  do {                                                                      \
    const float4 xv0 = *(const float4*)(smb + bxq[Q] + (B) * 2048 + 0);     \
    const float4 xv1 = *(const float4*)(smb + bxq[Q] + (B) * 2048 + 512);   \
    const float4 xv2 = *(const float4*)(smb + bxq[Q] + (B) * 2048 + 1024);  \
    const float4 xv3 = *(const float4*)(smb + bxq[Q] + (B) * 2048 + 1536);  \
    _Pragma("unroll") for (int j = 0; j < 8; ++j) {                         \
      const float4 w =                                                      \
          *(const float4*)(wrow + (size_t)32768 * j + (KO) + (Q) * 4);      \
      acc[0][j] = fmaf(xv0.x, w.x, acc[0][j]);                              \
      acc[0][j] = fmaf(xv0.y, w.y, acc[0][j]);                              \
      acc[0][j] = fmaf(xv0.z, w.z, acc[0][j]);                              \
      acc[0][j] = fmaf(xv0.w, w.w, acc[0][j]);                              \
      acc[1][j] = fmaf(xv1.x, w.x, acc[1][j]);                              \
      acc[1][j] = fmaf(xv1.y, w.y, acc[1][j]);                              \
      acc[1][j] = fmaf(xv1.z, w.z, acc[1][j]);                              \
      acc[1][j] = fmaf(xv1.w, w.w, acc[1][j]);                              \
      acc[2][j] = fmaf(xv2.x, w.x, acc[2][j]);                              \
      acc[2][j] = fmaf(xv2.y, w.y, acc[2][j]);                              \
      acc[2][j] = fmaf(xv2.z, w.z, acc[2][j]);                              \
      acc[2][j] = fmaf(xv2.w, w.w, acc[2][j]);                              \
      acc[3][j] = fmaf(xv3.x, w.x, acc[3][j]);                              \
      acc[3][j] = fmaf(xv3.y, w.y, acc[3][j]);                              \
      acc[3][j] = fmaf(xv3.z, w.z, acc[3][j]);                              \
      acc[3][j] = fmaf(xv3.w, w.w, acc[3][j]);                              \
    }                                                                       \
  } while (0)

  ISSUE(0, 0);  // prologue: chunk 0 -> buf 0

  // main loop: wave-private pipeline, no barriers. At each counted wait the
  // only outstanding VMEM ops are the two DMA pairs (w loads are all
  // register-consumed before the asm) -> vmcnt(2) = "previous DMA done".
#pragma unroll 1
  for (int cc = 0; cc < NCH; cc += 2) {
    const int k0 = cc * KC;
    ISSUE(1, cc + 1);
    asm volatile("s_waitcnt vmcnt(2)" ::: "memory");
    QUADOP(0, 0, k0);
    QUADOP(0, 1, k0);
    QUADOP(0, 2, k0);
    QUADOP(0, 3, k0);
    if (cc + 2 < NCH) {
      ISSUE(0, cc + 2);
      asm volatile("s_waitcnt vmcnt(2)" ::: "memory");
    } else {
      asm volatile("s_waitcnt vmcnt(0)" ::: "memory");
    }
    QUADOP(1, 0, k0 + KC);
    QUADOP(1, 1, k0 + KC);
    QUADOP(1, 2, k0 + KC);
    QUADOP(1, 3, k0 + KC);
  }
#undef QUADOP
#undef ISSUE

  __syncthreads();  // staging dies; logit planes alias it

  // partial logits: plane[kq][tok 64][LGSTR]; row h*32+s+8t, col g+8j
  {
    float* pl = &smem[kq * LGPL];
#pragma unroll
    for (int t = 0; t < 4; ++t)
#pragma unroll
      for (int j = 0; j < 8; ++j)
        pl[(h * 32 + s + 8 * t) * LGSTR + g + 8 * j] = acc[t][j];
  }
  __syncthreads();

  // epilogue: wave wid -> tokens wid*8..+7; lane == expert
  float psum_local = 0.f, cnt_local = 0.f;
  float* out_v = out;                // (NTOK, 2) top-k vals
  float* out_i = out + NTOK * TOPK;  // (NTOK, 2) top-k idx as float
#pragma unroll 1
  for (int ii = 0; ii < 8; ++ii) {
    const int t = wid * 8 + ii;
    float v = smem[0 * LGPL + t * LGSTR + lane] +
              smem[1 * LGPL + t * LGSTR + lane] +
              smem[2 * LGPL + t * LGSTR + lane] +
              smem[3 * LGPL + t * LGSTR + lane];
    float m = v;
#pragma unroll
    for (int sh = 32; sh > 0; sh >>= 1) m = fmaxf(m, __shfl_xor(m, sh, 64));
    float ex = expf(v - m);
    float ssum = ex;
#pragma unroll
    for (int sh = 32; sh > 0; sh >>= 1) ssum += __shfl_xor(ssum, sh, 64);
    float p = ex / ssum;
    psum_local += p;

    float v1 = p; int i1 = lane;  // top-1, ties -> lowest index
#pragma unroll
    for (int sh = 32; sh > 0; sh >>= 1) {
      float ov = __shfl_xor(v1, sh, 64);
      int oi = __shfl_xor(i1, sh, 64);
      if (ov > v1 || (ov == v1 && oi < i1)) { v1 = ov; i1 = oi; }
    }
    float v2 = (lane == i1) ? -INFINITY : p; int i2 = lane;  // top-2
#pragma unroll
    for (int sh = 32; sh > 0; sh >>= 1) {
      float ov = __shfl_xor(v2, sh, 64);
      int oi = __shfl_xor(i2, sh, 64);
      if (ov > v2 || (ov == v2 && oi < i2)) { v2 = ov; i2 = oi; }
    }
    cnt_local += (lane == i1 ? 1.f : 0.f) + (lane == i2 ? 1.f : 0.f);
    if (lane == 0) {
      const int tg = tok0 + t;
      out_v[tg * 2 + 0] = v1;
      out_v[tg * 2 + 1] = v2;
      out_i[tg * 2 + 0] = (float)i1;
      out_i[tg * 2 + 1] = (float)i2;
    }
  }
  // loss partials: ws[0:64] = pick counts, ws[64:128] = prob sums
  atomicAdd(ws + lane, cnt_local);
  atomicAdd(ws + NE + lane, psum_local);
}

__global__ void loss_kernel(const float* __restrict__ ws,
                            float* __restrict__ out) {
  const int lane = threadIdx.x & 63;
  float f = ws[lane] * (1.f / (float)(NTOK * TOPK));
  float p = ws[NE + lane] * (1.f / (float)NTOK);
  float v = f * p;  // loss = E * mean_i(f_i p_i) = sum_i f_i p_i
#pragma unroll
  for (int sh = 32; sh > 0; sh >>= 1) v += __shfl_xor(v, sh, 64);
  if (lane == 0) out[NTOK * TOPK * 2] = v;
}

extern "C" void kernel_launch(void* const* d_in, const int* in_sizes, int n_in,
                              void* d_out, int out_size, void* d_ws,
                              size_t ws_size, hipStream_t stream) {
  const float* x = (const float*)d_in[0];
  const float* gw = (const float*)d_in[1];
  float* out = (float*)d_out;
  float* ws = (float*)d_ws;

  hipMemsetAsync(d_ws, 0, 2 * NE * sizeof(float), stream);
  router_kernel<<<NTOK / TOKPB, BLOCK, 0, stream>>>(x, gw, out, ws);
  loss_kernel<<<1, 64, 0, stream>>>(ws, out);
}